// Round 5
// baseline (2143.253 us; speedup 1.0000x reference)
//
#include <hip/hip_runtime.h>

// DecoderRNN v5: 3-layer GRU, B=32768, H=100, 21 steps, VOCAB=20.
// Block = 4 waves x 64 batch rows; grid 512 = 2 blocks/CU. STATIC 64KB LDS
// (X0/H0/H1/H2 [64][128] bf16, 16B-chunk XOR swizzle) pins occupancy at
// 2 waves/SIMD -> compiler allocates up to 256 VGPR (v3/v4 failed at 128).
// Each wave owns 2 n-tiles of 16 (w3: tile6 + logits in its slot-B regs).
// K = 100+bias padded to 128 = 4 x k32 MFMA; biases in weight col 100 vs
// h[.][100]==1.0. Weights held in regs across the phase's 4 grps.
// Deferred h-writes (staged in 16 VGPR) -> 2 barriers/phase.

#define NTHR 256
#define NBLK 512
#define ROWS_PB 64

// wp (u16) offsets
#define OFF_PROJ 0                 // [112][128]
#define OFF_IH0  14336             // each [336][128]: row g*112+nn, col 100 = bias
#define OFF_HH0  57344
#define OFF_IH1  100352
#define OFF_HH1  143360
#define OFF_IH2  186368
#define OFF_HH2  229376
#define OFF_OUT  272384            // [32][128], col 100 = b_out
#define WP_TOTAL 276480

// LDS (u16): 4 buffers [64][128]
#define X0_OFF   0
#define H0_OFF   8192
#define H1_OFF   16384
#define H2_OFF   24576
#define SMEM_U16 32768             // 65536 B static

using frag8 = __attribute__((ext_vector_type(8))) short;
using frag4 = __attribute__((ext_vector_type(4))) short;
using f32x4 = __attribute__((ext_vector_type(4))) float;

struct G4  { frag8 a, b, c, d; };
struct T24 { G4 ir, iz, inn, hr, hz, hn; };

__device__ __forceinline__ unsigned short f2b(float f) {
    union { float f; unsigned u; } v; v.f = f;
    unsigned r = v.u + 0x7FFF + ((v.u >> 16) & 1);   // RNE
    return (unsigned short)(r >> 16);
}
__device__ __forceinline__ float b2f(unsigned short b) {
    union { unsigned u; float f; } v; v.u = ((unsigned)b) << 16; return v.f;
}
__device__ __forceinline__ float sigm(float x) { return 1.f / (1.f + __expf(-x)); }
__device__ __forceinline__ float tanh_fast(float x) { return 2.f / (1.f + __expf(-2.f * x)) - 1.f; }

__device__ __forceinline__ f32x4 mfma32(frag8 a, frag8 b, f32x4 c) {
    return __builtin_amdgcn_mfma_f32_16x16x32_bf16(a, b, c, 0, 0, 0);
}
__device__ __forceinline__ f32x4 dot4(const G4& w, const G4& s, f32x4 acc) {
    acc = mfma32(w.a, s.a, acc); acc = mfma32(w.b, s.b, acc);
    acc = mfma32(w.c, s.c, acc); return mfma32(w.d, s.d, acc);
}

// ---------------- weight prep: f32 -> bf16, padded, bias in col 100 ----------------
__global__ void prep_kernel(const float* __restrict__ w_proj,
    const float* __restrict__ wih0, const float* __restrict__ bih0,
    const float* __restrict__ whh0, const float* __restrict__ bhh0,
    const float* __restrict__ wih1, const float* __restrict__ bih1,
    const float* __restrict__ whh1, const float* __restrict__ bhh1,
    const float* __restrict__ wih2, const float* __restrict__ bih2,
    const float* __restrict__ whh2, const float* __restrict__ bhh2,
    const float* __restrict__ w_out, const float* __restrict__ b_out,
    unsigned short* __restrict__ dst)
{
    int idx = blockIdx.x * 256 + threadIdx.x;
    if (idx >= WP_TOTAL) return;
    float v = 0.f;
    if (idx < OFF_IH0) {
        int n = idx >> 7, k = idx & 127;
        if (n < 100) v = w_proj[n * 128 + k];
    } else if (idx < OFF_OUT) {
        int r = idx - OFF_IH0;
        int mi = r / 43008;
        int e  = r - mi * 43008;
        int n = e >> 7, k = e & 127;
        int g = n / 112, nn = n - g * 112;
        if (nn < 100) {
            const float* W; const float* Bv;
            switch (mi) {
                case 0: W = wih0; Bv = bih0; break;
                case 1: W = whh0; Bv = bhh0; break;
                case 2: W = wih1; Bv = bih1; break;
                case 3: W = whh1; Bv = bhh1; break;
                case 4: W = wih2; Bv = bih2; break;
                default: W = whh2; Bv = bhh2; break;
            }
            if (k < 100) v = W[(g * 100 + nn) * 100 + k];
            else if (k == 100) v = Bv[g * 100 + nn];
        }
    } else {
        int e = idx - OFF_OUT;
        int n = e >> 7, k = e & 127;
        if (n < 20) {
            if (k < 100) v = w_out[n * 100 + k];
            else if (k == 100) v = b_out[n];
        }
    }
    dst[idx] = f2b(v);
}

// ---------------- LDS helpers (swizzled) ----------------
// logical u16 col cu of row r stored at chunk (cu>>3) ^ (r&7)
__device__ __forceinline__ int hsw(int buf, int grp, int r, int cu) {
    int row = grp * 16 + r;
    return buf + row * 128 + ((((cu >> 3) ^ (row & 7)) << 3) | (cu & 7));
}
__device__ __forceinline__ G4 ldSG4(const unsigned short* sm, int buf, int grp, int c16, int g4) {
    const unsigned short* p = sm + buf + (grp * 16 + c16) * 128;
    int x = c16 & 7;
    G4 s;
    s.a = *(const frag8*)(p + ((g4 ^ x) << 3));
    s.b = *(const frag8*)(p + (((4 + g4) ^ x) << 3));
    s.c = *(const frag8*)(p + (((8 + g4) ^ x) << 3));
    s.d = *(const frag8*)(p + (((12 + g4) ^ x) << 3));
    return s;
}

// ---------------- weight loaders ----------------
__device__ __forceinline__ G4 ldWG4(const unsigned short* __restrict__ m, int g, int ro, int g4) {
    const unsigned short* p = m + (size_t)(g * 112 + ro) * 128 + g4 * 8;
    G4 w;
    w.a = *(const frag8*)p;        w.b = *(const frag8*)(p + 32);
    w.c = *(const frag8*)(p + 64); w.d = *(const frag8*)(p + 96);
    return w;
}
__device__ __forceinline__ void load_tile(T24& T, const unsigned short* __restrict__ wih,
                                          const unsigned short* __restrict__ whh, int ro, int g4) {
    T.ir = ldWG4(wih, 0, ro, g4); T.iz = ldWG4(wih, 1, ro, g4); T.inn = ldWG4(wih, 2, ro, g4);
    T.hr = ldWG4(whh, 0, ro, g4); T.hz = ldWG4(whh, 1, ro, g4); T.hn  = ldWG4(whh, 2, ro, g4);
}

__device__ __forceinline__ frag4 comp_tile(const T24& T, const G4& S, const G4& D, frag4 hold) {
    f32x4 ar = {0.f, 0.f, 0.f, 0.f}, az = ar, anx = ar, anh = ar;
    ar  = dot4(T.ir,  S, ar);  az  = dot4(T.iz, S, az);  anx = dot4(T.inn, S, anx);
    ar  = dot4(T.hr,  D, ar);  az  = dot4(T.hz, D, az);  anh = dot4(T.hn,  D, anh);
    frag4 hn;
#pragma unroll
    for (int j = 0; j < 4; ++j) {
        float r  = sigm(ar[j]);
        float z  = sigm(az[j]);
        float nn = tanh_fast(anx[j] + r * anh[j]);
        float ho = b2f((unsigned short)hold[j]);
        hn[j] = (short)f2b(nn + z * (ho - nn));
    }
    return hn;
}

// ---------------- one GRU layer phase (2 barriers) ----------------
template<bool PH0>
__device__ __forceinline__ void gru_phase(unsigned short* sm, int HS, int HD,
    const unsigned short* __restrict__ wih, const unsigned short* __restrict__ whh,
    const unsigned short* __restrict__ wout, int lt,
    float* __restrict__ out, int rbase, int wid, int c16, int g4)
{
    const bool hasB = (wid < 3);
    const int  tA   = hasB ? 2 * wid : 6;
    const int  roA  = tA * 16 + c16;
    const int  roB  = (2 * wid + 1) * 16 + c16;
    const int  nbA  = tA * 16 + g4 * 4;
    const int  nbB  = (2 * wid + 1) * 16 + g4 * 4;
    const bool valdA = (nbA < 100);

    T24 TA; load_tile(TA, wih, whh, roA, g4);
    T24 TB;
    if (hasB) load_tile(TB, wih, whh, roB, g4);
    else if (PH0) { TB.ir = ldWG4(wout, 0, c16, g4); TB.iz = ldWG4(wout, 0, 16 + c16, g4); }

    __syncthreads();                              // B0: prev-phase writes visible
    frag4 hnA[4], hnB[4];
#pragma unroll
    for (int grp = 0; grp < 4; ++grp) {
        G4 S = ldSG4(sm, HS, grp, c16, g4);
        G4 D = ldSG4(sm, HD, grp, c16, g4);
        frag4 holdA = *(const frag4*)(sm + hsw(HD, grp, c16, nbA));
        hnA[grp] = comp_tile(TA, S, D, holdA);
        if (hasB) {
            frag4 holdB = *(const frag4*)(sm + hsw(HD, grp, c16, nbB));
            hnB[grp] = comp_tile(TB, S, D, holdB);
        } else if (PH0 && lt >= 0) {
            G4 L = ldSG4(sm, H2_OFF, grp, c16, g4);
            f32x4 a0 = {0.f, 0.f, 0.f, 0.f}, a1 = a0;
            a0 = dot4(TB.ir, L, a0);
            a1 = dot4(TB.iz, L, a1);
            float* po = out + (size_t)(rbase + grp * 16 + c16) * 420 + lt * 20;
            *(f32x4*)(po + g4 * 4) = a0;          // vocab 4*g4 .. +4
            if (g4 == 0) *(f32x4*)(po + 16) = a1; // vocab 16..19
        }
    }
    __syncthreads();                              // B1: all reads of old HD done
#pragma unroll
    for (int grp = 0; grp < 4; ++grp) {
        if (valdA) *(frag4*)(sm + hsw(HD, grp, c16, nbA)) = hnA[grp];
        if (hasB)  *(frag4*)(sm + hsw(HD, grp, c16, nbB)) = hnB[grp];
    }
}

// ---------------- main kernel ----------------
__global__ void __launch_bounds__(NTHR, 2) rnn_kernel(
    const float* __restrict__ enc,
    const float* __restrict__ b_proj,
    const unsigned short* __restrict__ wp,
    float* __restrict__ out)
{
    __shared__ unsigned short sm[SMEM_U16];
    const int tid  = threadIdx.x;
    const int lane = tid & 63;
    const int wid  = tid >> 6;
    const int c16  = lane & 15;
    const int g4   = lane >> 4;
    const int rbase = blockIdx.x * ROWS_PB;
    const bool hasB = (wid < 3);
    const int  tA   = hasB ? 2 * wid : 6;
    const int  roA  = tA * 16 + c16;
    const int  roB  = (2 * wid + 1) * 16 + c16;
    const int  nbA  = tA * 16 + g4 * 4;
    const int  nbB  = (2 * wid + 1) * 16 + g4 * 4;
    const bool valdA = (nbA < 100);

    // ---- init LDS: zeros, logical col 100 = 1.0 (bias) ----
    for (int i = tid; i < SMEM_U16; i += NTHR) {
        int r  = (i >> 7) & 63;
        int cu = i & 127;
        int lcol = ((((cu >> 3) ^ (r & 7)) << 3) | (cu & 7));
        sm[i] = (lcol == 100) ? (unsigned short)0x3F80 : (unsigned short)0;
    }
    __syncthreads();

    // ---- prologue: x0 = enc @ w_proj^T + b_proj -> X0 (K=128 exact) ----
    {
        G4 PA = ldWG4(wp + OFF_PROJ, 0, roA, g4);
        G4 PB;
        if (hasB) PB = ldWG4(wp + OFF_PROJ, 0, roB, g4);
        f32x4 bpA = {0.f, 0.f, 0.f, 0.f}, bpB = bpA;
        if (valdA) bpA = *(const f32x4*)(b_proj + nbA);
        if (hasB)  bpB = *(const f32x4*)(b_proj + nbB);
#pragma unroll 1
        for (int grp = 0; grp < 4; ++grp) {
            const float* ep = enc + (size_t)(rbase + grp * 16 + c16) * 128 + g4 * 8;
            G4 E;
            {
                frag8 e0, e1, e2, e3;
#pragma unroll
                for (int j = 0; j < 8; ++j) {
                    e0[j] = (short)f2b(ep[j]);      e1[j] = (short)f2b(ep[32 + j]);
                    e2[j] = (short)f2b(ep[64 + j]); e3[j] = (short)f2b(ep[96 + j]);
                }
                E.a = e0; E.b = e1; E.c = e2; E.d = e3;
            }
            f32x4 acc = dot4(PA, E, bpA);
            if (valdA) {
                frag4 xv;
#pragma unroll
                for (int j = 0; j < 4; ++j) xv[j] = (short)f2b(acc[j]);
                *(frag4*)(sm + hsw(X0_OFF, grp, c16, nbA)) = xv;
            }
            if (hasB) {
                f32x4 accB = dot4(PB, E, bpB);
                frag4 xv;
#pragma unroll
                for (int j = 0; j < 4; ++j) xv[j] = (short)f2b(accB[j]);
                *(frag4*)(sm + hsw(X0_OFF, grp, c16, nbB)) = xv;
            }
        }
    }
    // (phase0's B0 provides the needed sync)

    // ---- time loop ----
#pragma unroll 1
    for (int t = 0; t < 21; ++t) {
        gru_phase<true >(sm, X0_OFF, H0_OFF, wp + OFF_IH0, wp + OFF_HH0,
                         wp + OFF_OUT, t - 1, out, rbase, wid, c16, g4);
        gru_phase<false>(sm, H0_OFF, H1_OFF, wp + OFF_IH1, wp + OFF_HH1,
                         wp, -1, out, rbase, wid, c16, g4);
        gru_phase<false>(sm, H1_OFF, H2_OFF, wp + OFF_IH2, wp + OFF_HH2,
                         wp, -1, out, rbase, wid, c16, g4);
    }

    // ---- tail: logits for t=20 (wave 3) ----
    __syncthreads();
    if (wid == 3) {
        G4 O0 = ldWG4(wp + OFF_OUT, 0, c16, g4);
        G4 O1 = ldWG4(wp + OFF_OUT, 0, 16 + c16, g4);
#pragma unroll 1
        for (int grp = 0; grp < 4; ++grp) {
            G4 L = ldSG4(sm, H2_OFF, grp, c16, g4);
            f32x4 a0 = {0.f, 0.f, 0.f, 0.f}, a1 = a0;
            a0 = dot4(O0, L, a0);
            a1 = dot4(O1, L, a1);
            float* po = out + (size_t)(rbase + grp * 16 + c16) * 420 + 20 * 20;
            *(f32x4*)(po + g4 * 4) = a0;
            if (g4 == 0) *(f32x4*)(po + 16) = a1;
        }
    }
}

extern "C" void kernel_launch(void* const* d_in, const int* in_sizes, int n_in,
                              void* d_out, int out_size, void* d_ws, size_t ws_size,
                              hipStream_t stream) {
    const float* enc    = (const float*)d_in[0];
    const float* w_proj = (const float*)d_in[1];
    const float* b_proj = (const float*)d_in[2];
    const float* wih0   = (const float*)d_in[3];
    const float* whh0   = (const float*)d_in[4];
    const float* bih0   = (const float*)d_in[5];
    const float* bhh0   = (const float*)d_in[6];
    const float* wih1   = (const float*)d_in[7];
    const float* whh1   = (const float*)d_in[8];
    const float* bih1   = (const float*)d_in[9];
    const float* bhh1   = (const float*)d_in[10];
    const float* wih2   = (const float*)d_in[11];
    const float* whh2   = (const float*)d_in[12];
    const float* bih2   = (const float*)d_in[13];
    const float* bhh2   = (const float*)d_in[14];
    const float* w_out  = (const float*)d_in[15];
    const float* b_out  = (const float*)d_in[16];
    unsigned short* wpd = (unsigned short*)d_ws;   // 552,960 B used
    float* out          = (float*)d_out;

    prep_kernel<<<(WP_TOTAL + 255) / 256, 256, 0, stream>>>(
        w_proj, wih0, bih0, whh0, bhh0, wih1, bih1, whh1, bhh1,
        wih2, bih2, whh2, bhh2, w_out, b_out, wpd);

    rnn_kernel<<<NBLK, NTHR, 0, stream>>>(enc, b_proj, wpd, out);
}

// Round 6
// 588.077 us; speedup vs baseline: 3.6445x; 3.6445x over previous
//
#include <hip/hip_runtime.h>

// DecoderRNN v6: 3-layer GRU, B=32768, H=100, 21 steps, VOCAB=20.
// Block = 8 waves x 128 batch rows, grid 256 = 1 block/CU.
// STATIC 128KB LDS (X0/H0/H1/H2 [128][128] bf16, XOR-swizzled) makes the
// 1-block/CU occupancy visible to the compiler -> 256-VGPR budget ->
// per-phase weights (24 frag8 = 96 VGPR) stay RESIDENT across all 8 grps
// (v3 rematerialized them 8x/phase; v4/v5 spilled).
// 2 barriers/phase via deferred h-writes staged in registers.
// Activations in exp2 form: gate weights pre-scaled by log2e (r,z) and
// 2*log2e (n) so sigmoid/tanh need only v_exp_f32 + v_rcp_f32.

#define NTHR 512
#define NBLK 256
#define ROWS_PB 128

// wp (u16) offsets
#define OFF_PROJ 0                 // [112][128]
#define OFF_IH0  14336             // each [336][128]: row g*112+nn, col 100 = bias
#define OFF_HH0  57344
#define OFF_IH1  100352
#define OFF_HH1  143360
#define OFF_IH2  186368
#define OFF_HH2  229376
#define OFF_OUT  272384            // [32][128], col 100 = b_out (rows 20..31 zero)
#define WP_TOTAL 276480

// LDS (u16): 4 buffers [128][128], 16B-chunk XOR swizzle
#define X0_OFF   0
#define H0_OFF   16384
#define H1_OFF   32768
#define H2_OFF   49152
#define SMEM_U16 65536             // 131072 B static

using frag8 = __attribute__((ext_vector_type(8))) short;
using frag4 = __attribute__((ext_vector_type(4))) short;
using f32x4 = __attribute__((ext_vector_type(4))) float;

struct G4 { frag8 a, b, c, d; };

__device__ __forceinline__ unsigned short f2b(float f) {
    union { float f; unsigned u; } v; v.f = f;
    unsigned r = v.u + 0x7FFF + ((v.u >> 16) & 1);   // RNE
    return (unsigned short)(r >> 16);
}
__device__ __forceinline__ float b2f(unsigned short b) {
    union { unsigned u; float f; } v; v.u = ((unsigned)b) << 16; return v.f;
}

__device__ __forceinline__ f32x4 mfma32(frag8 a, frag8 b, f32x4 c) {
    return __builtin_amdgcn_mfma_f32_16x16x32_bf16(a, b, c, 0, 0, 0);
}
__device__ __forceinline__ f32x4 dot4(const G4& w, const G4& s, f32x4 acc) {
    acc = mfma32(w.a, s.a, acc); acc = mfma32(w.b, s.b, acc);
    acc = mfma32(w.c, s.c, acc); return mfma32(w.d, s.d, acc);
}

// ---------------- weight prep: f32 -> bf16, padded, bias col 100, prescaled ----
__global__ void prep_kernel(const float* __restrict__ w_proj,
    const float* __restrict__ wih0, const float* __restrict__ bih0,
    const float* __restrict__ whh0, const float* __restrict__ bhh0,
    const float* __restrict__ wih1, const float* __restrict__ bih1,
    const float* __restrict__ whh1, const float* __restrict__ bhh1,
    const float* __restrict__ wih2, const float* __restrict__ bih2,
    const float* __restrict__ whh2, const float* __restrict__ bhh2,
    const float* __restrict__ w_out, const float* __restrict__ b_out,
    unsigned short* __restrict__ dst)
{
    const float LOG2E  = 1.4426950408889634f;
    const float LOG2E2 = 2.8853900817779268f;
    int idx = blockIdx.x * 256 + threadIdx.x;
    if (idx >= WP_TOTAL) return;
    float v = 0.f;
    if (idx < OFF_IH0) {
        int n = idx >> 7, k = idx & 127;
        if (n < 100) v = w_proj[n * 128 + k];
    } else if (idx < OFF_OUT) {
        int r = idx - OFF_IH0;
        int mi = r / 43008;
        int e  = r - mi * 43008;
        int n = e >> 7, k = e & 127;
        int g = n / 112, nn = n - g * 112;
        if (nn < 100) {
            const float* W; const float* Bv;
            switch (mi) {
                case 0: W = wih0; Bv = bih0; break;
                case 1: W = whh0; Bv = bhh0; break;
                case 2: W = wih1; Bv = bih1; break;
                case 3: W = whh1; Bv = bhh1; break;
                case 4: W = wih2; Bv = bih2; break;
                default: W = whh2; Bv = bhh2; break;
            }
            if (k < 100) v = W[(g * 100 + nn) * 100 + k];
            else if (k == 100) v = Bv[g * 100 + nn];
            v *= (g == 2) ? LOG2E2 : LOG2E;       // exp2-form activations
        }
    } else {
        int e = idx - OFF_OUT;
        int n = e >> 7, k = e & 127;
        if (n < 20) {
            if (k < 100) v = w_out[n * 100 + k];
            else if (k == 100) v = b_out[n];
        }
    }
    dst[idx] = f2b(v);
}

// ---------------- LDS helpers (swizzled) ----------------
// logical u16 col cu of row r stored at 8-u16 chunk (cu>>3) ^ (r&7)
__device__ __forceinline__ int hsw(int buf, int grp, int r, int cu) {
    int row = grp * 16 + r;
    return buf + row * 128 + ((((cu >> 3) ^ (row & 7)) << 3) | (cu & 7));
}
__device__ __forceinline__ G4 ldSG4(const unsigned short* sm, int buf, int grp, int c16, int g4) {
    const unsigned short* p = sm + buf + (grp * 16 + c16) * 128;
    int x = c16 & 7;
    G4 s;
    s.a = *(const frag8*)(p + ((g4 ^ x) << 3));
    s.b = *(const frag8*)(p + (((4 + g4) ^ x) << 3));
    s.c = *(const frag8*)(p + (((8 + g4) ^ x) << 3));
    s.d = *(const frag8*)(p + (((12 + g4) ^ x) << 3));
    return s;
}

// ---------------- weight loader ----------------
__device__ __forceinline__ G4 ldWG4(const unsigned short* __restrict__ m, int g, int ro, int g4) {
    const unsigned short* p = m + (size_t)(g * 112 + ro) * 128 + g4 * 8;
    G4 w;
    w.a = *(const frag8*)p;        w.b = *(const frag8*)(p + 32);
    w.c = *(const frag8*)(p + 64); w.d = *(const frag8*)(p + 96);
    return w;
}

__device__ __forceinline__ void logits_one(const unsigned short* sm,
        const G4& O0, const G4& O1, int grp, int lt,
        float* __restrict__ out, int rbase, int c16, int g4) {
    G4 L = ldSG4(sm, H2_OFF, grp, c16, g4);
    f32x4 a0 = {0.f, 0.f, 0.f, 0.f}, a1 = a0;
    a0 = dot4(O0, L, a0);
    a1 = dot4(O1, L, a1);
    float* po = out + (size_t)(rbase + grp * 16 + c16) * 420 + lt * 20;
    *(f32x4*)(po + g4 * 4) = a0;           // vocab 4*g4 .. +4
    if (g4 == 0) *(f32x4*)(po + 16) = a1;  // vocab 16..19
}

// ---------------- one GRU layer phase (2 barriers) ----------------
template<bool PH0>
__device__ __forceinline__ void gru_phase(unsigned short* sm, int HS, int HD,
    const unsigned short* __restrict__ wih, const unsigned short* __restrict__ whh,
    const G4* O, int lt, float* __restrict__ out, int rbase,
    bool owner, bool vald, int c16, int g4, int ro, int nbase)
{
    G4 Wi[3], Wh[3];
    if (owner) {
#pragma unroll
        for (int g = 0; g < 3; ++g) { Wi[g] = ldWG4(wih, g, ro, g4); Wh[g] = ldWG4(whh, g, ro, g4); }
    }
    __syncthreads();                              // B0: prev-phase writes visible
    frag4 hn[8];
#pragma unroll
    for (int grp = 0; grp < 8; ++grp) {
        if (owner) {
            G4 S = ldSG4(sm, HS, grp, c16, g4);
            G4 D = ldSG4(sm, HD, grp, c16, g4);
            f32x4 ar = {0.f, 0.f, 0.f, 0.f}, az = ar, anx = ar, anh = ar;
            ar  = dot4(Wi[0], S, ar);   ar  = dot4(Wh[0], D, ar);
            az  = dot4(Wi[1], S, az);   az  = dot4(Wh[1], D, az);
            anx = dot4(Wi[2], S, anx);  anh = dot4(Wh[2], D, anh);
            frag4 hold = *(const frag4*)(sm + hsw(HD, grp, c16, nbase));
#pragma unroll
            for (int j = 0; j < 4; ++j) {
                float r  = __builtin_amdgcn_rcpf(1.f + __builtin_amdgcn_exp2f(-ar[j]));
                float z  = __builtin_amdgcn_rcpf(1.f + __builtin_amdgcn_exp2f(-az[j]));
                float y  = anx[j] + r * anh[j];
                float nn = 1.f - 2.f * __builtin_amdgcn_rcpf(1.f + __builtin_amdgcn_exp2f(y));
                float ho = b2f((unsigned short)hold[j]);
                hn[grp][j] = (short)f2b(nn + z * (ho - nn));
            }
        } else if (PH0 && lt >= 0) {
            logits_one(sm, O[0], O[1], grp, lt, out, rbase, c16, g4);
        }
    }
    __syncthreads();                              // B1: all reads of old HD done
    if (owner && vald) {
#pragma unroll
        for (int grp = 0; grp < 8; ++grp)
            *(frag4*)(sm + hsw(HD, grp, c16, nbase)) = hn[grp];
    }
}

// ---------------- main kernel ----------------
__global__ void __launch_bounds__(NTHR, 2) rnn_kernel(
    const float* __restrict__ enc,
    const float* __restrict__ b_proj,
    const unsigned short* __restrict__ wp,
    float* __restrict__ out)
{
    __shared__ unsigned short sm[SMEM_U16];       // 128 KB static -> 1 block/CU visible
    const int tid  = threadIdx.x;
    const int lane = tid & 63;
    const int wid  = tid >> 6;
    const int c16  = lane & 15;
    const int g4   = lane >> 4;
    const int rbase = blockIdx.x * ROWS_PB;
    const bool owner = (wid < 7);
    const int tw    = owner ? wid : 0;
    const int ro    = tw * 16 + c16;
    const int nbase = tw * 16 + g4 * 4;
    const bool vald = owner && (nbase < 100);

    // ---- init LDS: zeros, logical col 100 = 1.0 (bias) ----
    for (int i = tid; i < SMEM_U16; i += NTHR) {
        int r  = (i >> 7) & 127;
        int cu = i & 127;
        int lcol = ((((cu >> 3) ^ (r & 7)) << 3) | (cu & 7));
        sm[i] = (lcol == 100) ? (unsigned short)0x3F80 : (unsigned short)0;
    }

    // ---- wave 7: persistent w_out fragments ----
    G4 O[2];
    if (!owner) {
        O[0] = ldWG4(wp + OFF_OUT, 0, c16, g4);
        O[1] = ldWG4(wp + OFF_OUT, 0, 16 + c16, g4);
    }
    __syncthreads();

    // ---- prologue: x0 = enc @ w_proj^T + b_proj -> X0 (K=128 exact) ----
    if (owner) {
        G4 P = ldWG4(wp + OFF_PROJ, 0, ro, g4);
        f32x4 bp = {0.f, 0.f, 0.f, 0.f};
        if (vald) bp = *(const f32x4*)(b_proj + nbase);
#pragma unroll 1
        for (int grp = 0; grp < 8; ++grp) {
            const float* ep = enc + (size_t)(rbase + grp * 16 + c16) * 128 + g4 * 8;
            G4 E;
            {
                frag8 e0, e1, e2, e3;
#pragma unroll
                for (int j = 0; j < 8; ++j) {
                    e0[j] = (short)f2b(ep[j]);      e1[j] = (short)f2b(ep[32 + j]);
                    e2[j] = (short)f2b(ep[64 + j]); e3[j] = (short)f2b(ep[96 + j]);
                }
                E.a = e0; E.b = e1; E.c = e2; E.d = e3;
            }
            f32x4 acc = dot4(P, E, bp);
            if (vald) {
                frag4 xv;
#pragma unroll
                for (int j = 0; j < 4; ++j) xv[j] = (short)f2b(acc[j]);
                *(frag4*)(sm + hsw(X0_OFF, grp, c16, nbase)) = xv;
            }
        }
    }
    // (first phase's B0 provides the needed sync)

    // ---- time loop: three phases; wave 7 logits(t-1) during phase 0 ----
#pragma unroll 1
    for (int t = 0; t < 21; ++t) {
        gru_phase<true >(sm, X0_OFF, H0_OFF, wp + OFF_IH0, wp + OFF_HH0,
                         O, t - 1, out, rbase, owner, vald, c16, g4, ro, nbase);
        gru_phase<false>(sm, H0_OFF, H1_OFF, wp + OFF_IH1, wp + OFF_HH1,
                         O, -1, out, rbase, owner, vald, c16, g4, ro, nbase);
        gru_phase<false>(sm, H1_OFF, H2_OFF, wp + OFF_IH2, wp + OFF_HH2,
                         O, -1, out, rbase, owner, vald, c16, g4, ro, nbase);
    }

    // ---- tail: logits for t=20 (wave 7) ----
    __syncthreads();
    if (!owner) {
#pragma unroll 1
        for (int grp = 0; grp < 8; ++grp)
            logits_one(sm, O[0], O[1], grp, 20, out, rbase, c16, g4);
    }
}

extern "C" void kernel_launch(void* const* d_in, const int* in_sizes, int n_in,
                              void* d_out, int out_size, void* d_ws, size_t ws_size,
                              hipStream_t stream) {
    const float* enc    = (const float*)d_in[0];
    const float* w_proj = (const float*)d_in[1];
    const float* b_proj = (const float*)d_in[2];
    const float* wih0   = (const float*)d_in[3];
    const float* whh0   = (const float*)d_in[4];
    const float* bih0   = (const float*)d_in[5];
    const float* bhh0   = (const float*)d_in[6];
    const float* wih1   = (const float*)d_in[7];
    const float* whh1   = (const float*)d_in[8];
    const float* bih1   = (const float*)d_in[9];
    const float* bhh1   = (const float*)d_in[10];
    const float* bih2   = (const float*)d_in[13];
    const float* wih2   = (const float*)d_in[11];
    const float* whh2   = (const float*)d_in[12];
    const float* bhh2   = (const float*)d_in[14];
    const float* w_out  = (const float*)d_in[15];
    const float* b_out  = (const float*)d_in[16];
    unsigned short* wpd = (unsigned short*)d_ws;   // 552,960 B used
    float* out          = (float*)d_out;

    prep_kernel<<<(WP_TOTAL + 255) / 256, 256, 0, stream>>>(
        w_proj, wih0, bih0, whh0, bhh0, wih1, bih1, whh1, bhh1,
        wih2, bih2, whh2, bhh2, w_out, b_out, wpd);

    rnn_kernel<<<NBLK, NTHR, 0, stream>>>(enc, b_proj, wpd, out);
}